// Round 1
// baseline (489.328 us; speedup 1.0000x reference)
//
#include <hip/hip_runtime.h>

#define N_NODES 50000
#define N_EDGES 800000
#define CH 64
#define OUT_OFF_STD (N_NODES * CH)        // 3,200,000
#define OUT_OFF_KL  (2 * N_NODES * CH)    // 6,400,000

// ---------------------------------------------------------------------------
// Kernel A: reparameterized weights + KL reduction. One block, 256 threads.
// w = mu + eps * exp(ls);  kl = sum 0.5*(exp(2ls) + mu^2 - 2ls - 1)  (pv=1)
// ---------------------------------------------------------------------------
__global__ __launch_bounds__(256) void wkl_kernel(
    const float* __restrict__ mu_m, const float* __restrict__ ls_m,
    const float* __restrict__ eps_m,
    const float* __restrict__ mu_s, const float* __restrict__ ls_s,
    const float* __restrict__ eps_s,
    float* __restrict__ w_m, float* __restrict__ w_s,
    float* __restrict__ kl_out)
{
    float kl = 0.0f;
    for (int i = threadIdx.x; i < CH * CH; i += 256) {
        float mu = mu_m[i], ls = ls_m[i];
        w_m[i] = mu + eps_m[i] * expf(ls);
        kl += 0.5f * (expf(2.0f * ls) + mu * mu - 2.0f * ls - 1.0f);
        mu = mu_s[i]; ls = ls_s[i];
        w_s[i] = mu + eps_s[i] * expf(ls);
        kl += 0.5f * (expf(2.0f * ls) + mu * mu - 2.0f * ls - 1.0f);
    }
    // wave reduce (64 lanes), then cross-wave via LDS
    for (int off = 32; off > 0; off >>= 1)
        kl += __shfl_down(kl, off, 64);
    __shared__ float red[4];
    if ((threadIdx.x & 63) == 0) red[threadIdx.x >> 6] = kl;
    __syncthreads();
    if (threadIdx.x == 0)
        kl_out[0] = red[0] + red[1] + red[2] + red[3];
}

// ---------------------------------------------------------------------------
// Kernel B: fused dual GEMM. sup_m = mean @ Wm ; sup_v = (std^2) @ Wv.
// One wave per row; lane = output column. W matrices staged in LDS.
// x-row base made wave-uniform (readfirstlane) so loads can scalarize.
// ---------------------------------------------------------------------------
__global__ __launch_bounds__(256) void gemm_kernel(
    const float* __restrict__ mean, const float* __restrict__ stdv,
    const float* __restrict__ w_m_g, const float* __restrict__ w_s_g,
    float* __restrict__ sup_m, float* __restrict__ sup_v)
{
    __shared__ float Wm[CH * CH];
    __shared__ float Wv[CH * CH];
    for (int i = threadIdx.x; i < CH * CH; i += 256) {
        Wm[i] = w_m_g[i];
        Wv[i] = w_s_g[i];
    }
    __syncthreads();

    int row = blockIdx.x * 4 + (threadIdx.x >> 6);   // 4 waves/block, 1 row/wave
    if (row >= N_NODES) return;
    row = __builtin_amdgcn_readfirstlane(row);
    const int col = threadIdx.x & 63;

    const float4* xm = (const float4*)(mean + (size_t)row * CH);
    const float4* xs = (const float4*)(stdv + (size_t)row * CH);

    float accm = 0.0f, accv = 0.0f;
#pragma unroll
    for (int k4 = 0; k4 < CH / 4; ++k4) {
        float4 m4 = xm[k4];
        float4 s4 = xs[k4];
        const float* wmp = &Wm[(k4 * 4) * CH + col];
        const float* wvp = &Wv[(k4 * 4) * CH + col];
        accm += m4.x * wmp[0];
        accm += m4.y * wmp[CH];
        accm += m4.z * wmp[2 * CH];
        accm += m4.w * wmp[3 * CH];
        accv += (s4.x * s4.x) * wvp[0];
        accv += (s4.y * s4.y) * wvp[CH];
        accv += (s4.z * s4.z) * wvp[2 * CH];
        accv += (s4.w * s4.w) * wvp[3 * CH];
    }
    sup_m[(size_t)row * CH + col] = accm;
    sup_v[(size_t)row * CH + col] = accv;
}

// ---------------------------------------------------------------------------
// Kernel C: edge scatter. One wave per edge, lane = channel.
// mean branch uses w, var branch uses w^2. fp32 atomics into d_out halves.
// ---------------------------------------------------------------------------
__global__ __launch_bounds__(256) void scatter_kernel(
    const int* __restrict__ ei, const float* __restrict__ ew,
    const float* __restrict__ sup_m, const float* __restrict__ sup_v,
    float* __restrict__ out)
{
    int e = blockIdx.x * 4 + (threadIdx.x >> 6);     // 4 edges/block
    if (e >= N_EDGES) return;
    const int col = threadIdx.x & 63;
    int src = __builtin_amdgcn_readfirstlane(ei[e]);
    int dst = __builtin_amdgcn_readfirstlane(ei[N_EDGES + e]);
    float w = ew[e];
    float sm = sup_m[(size_t)src * CH + col];
    float sv = sup_v[(size_t)src * CH + col];
    atomicAdd(&out[(size_t)dst * CH + col], w * sm);
    atomicAdd(&out[OUT_OFF_STD + (size_t)dst * CH + col], (w * w) * sv);
}

// ---------------------------------------------------------------------------
// Kernel D: new_std = sqrt(exp(log_var) + 1e-6), in place on out[3.2M:6.4M].
// ---------------------------------------------------------------------------
__global__ __launch_bounds__(256) void finalize_kernel(float* __restrict__ p)
{
    int i = blockIdx.x * 256 + threadIdx.x;
    if (i < OUT_OFF_STD)
        p[i] = sqrtf(expf(p[i]) + 1e-6f);
}

extern "C" void kernel_launch(void* const* d_in, const int* in_sizes, int n_in,
                              void* d_out, int out_size, void* d_ws, size_t ws_size,
                              hipStream_t stream)
{
    const float* mean  = (const float*)d_in[0];
    const float* stdv  = (const float*)d_in[1];
    const int*   ei    = (const int*)d_in[2];
    const float* ew    = (const float*)d_in[3];
    const float* mu_m  = (const float*)d_in[4];
    const float* ls_m  = (const float*)d_in[5];
    const float* eps_m = (const float*)d_in[6];
    const float* mu_s  = (const float*)d_in[7];
    const float* ls_s  = (const float*)d_in[8];
    const float* eps_s = (const float*)d_in[9];

    float* out = (float*)d_out;
    float* ws  = (float*)d_ws;
    float* w_m   = ws;
    float* w_s   = ws + CH * CH;
    float* sup_m = ws + 2 * CH * CH;
    float* sup_v = sup_m + (size_t)N_NODES * CH;

    // zero the two accumulated output blocks (harness poisons with 0xAA)
    hipMemsetAsync(d_out, 0, (size_t)OUT_OFF_KL * sizeof(float), stream);

    wkl_kernel<<<1, 256, 0, stream>>>(mu_m, ls_m, eps_m, mu_s, ls_s, eps_s,
                                      w_m, w_s, out + OUT_OFF_KL);
    gemm_kernel<<<N_NODES / 4, 256, 0, stream>>>(mean, stdv, w_m, w_s,
                                                 sup_m, sup_v);
    scatter_kernel<<<N_EDGES / 4, 256, 0, stream>>>(ei, ew, sup_m, sup_v, out);
    finalize_kernel<<<OUT_OFF_STD / 256, 256, 0, stream>>>(out + OUT_OFF_STD);
}